// Round 4
// baseline (443.649 us; speedup 1.0000x reference)
//
#include <hip/hip_runtime.h>

#define B_TOTAL   8388608
#define THREADS   256
#define BLOCKS    4096
#define WPB       4                          // waves per block
#define GW_TOTAL  (BLOCKS * WPB)             // 16384 global waves
#define SPWI      256                        // samples per wave-iteration
#define WI_TOTAL  (B_TOTAL / SPWI)           // 32768 wave-iterations
#define ITERS     (WI_TOTAL / GW_TOTAL)      // 2 per wave

// d_ws layout: float sums[4] | unsigned int count
__global__ __launch_bounds__(THREADS) void trading_loss_fused(
    const float* __restrict__ preds,    // [B,3]
    const int*   __restrict__ targets,  // [B]
    const float* __restrict__ pc,       // [B]
    const float* __restrict__ td,       // [B]
    float*        __restrict__ sums,    // [4], zeroed
    unsigned int* __restrict__ count,   // zeroed
    float*        __restrict__ out)
{
    const int wave = threadIdx.x >> 6;
    const int l    = threadIdx.x & 63;
    const int gw   = blockIdx.x * WPB + wave;

    const float4* preds4 = reinterpret_cast<const float4*>(preds);
    const int4*   tg4    = reinterpret_cast<const int4*  >(targets);
    const float4* pc4    = reinterpret_cast<const float4*>(pc);
    const float4* td4    = reinterpret_cast<const float4*>(td);

    // wave-private staging: 192 float4s (3 KB) per wave
    __shared__ float4 stage[WPB][192];
    float4* st = stage[wave];

    float s_cew = 0.f, s_ce = 0.f, s_mw = 0.f, s_tr = 0.f;

    // -------- prologue: coalesced loads for iteration 0 --------
    int wi = gw;
    float4 A0 = preds4[(size_t)wi * 192 +   0 + l];
    float4 A1 = preds4[(size_t)wi * 192 +  64 + l];
    float4 A2 = preds4[(size_t)wi * 192 + 128 + l];
    int4   T  = tg4[(size_t)wi * 64 + l];
    float4 P  = pc4[(size_t)wi * 64 + l];
    float4 D  = td4[(size_t)wi * 64 + l];

    #pragma unroll
    for (int it = 0; it < ITERS; ++it) {
        __syncthreads();              // previous iteration's stage reads done
        st[  0 + l] = A0;
        st[ 64 + l] = A1;
        st[128 + l] = A2;

        // -------- prefetch next iteration (registers) --------
        float4 nA0, nA1, nA2, nP, nD; int4 nT;
        const int nwi = wi + GW_TOTAL;
        if (it + 1 < ITERS) {
            nA0 = preds4[(size_t)nwi * 192 +   0 + l];
            nA1 = preds4[(size_t)nwi * 192 +  64 + l];
            nA2 = preds4[(size_t)nwi * 192 + 128 + l];
            nT  = tg4[(size_t)nwi * 64 + l];
            nP  = pc4[(size_t)nwi * 64 + l];
            nD  = td4[(size_t)nwi * 64 + l];
        }

        __syncthreads();              // stage writes visible

        // per-lane contiguous 48 B from LDS (uniform bank-group usage)
        float4 r0 = st[3*l + 0];
        float4 r1 = st[3*l + 1];
        float4 r2 = st[3*l + 2];

        float p[12] = {r0.x,r0.y,r0.z,r0.w, r1.x,r1.y,r1.z,r1.w, r2.x,r2.y,r2.z,r2.w};
        int   tt[4]  = {T.x, T.y, T.z, T.w};
        float pcv[4] = {P.x, P.y, P.z, P.w};
        float tdv[4] = {D.x, D.y, D.z, D.w};

        #pragma unroll
        for (int j = 0; j < 4; ++j) {
            float p0 = p[j*3 + 0], p1 = p[j*3 + 1], p2 = p[j*3 + 2];
            float m  = fmaxf(fmaxf(p0, p1), p2);
            float e0 = __expf(p0 - m);
            float e1 = __expf(p1 - m);
            float e2 = __expf(p2 - m);
            float lse = __logf(e0 + e1 + e2);
            int   t  = tt[j];
            float pt = (t == 0) ? p0 : ((t == 1) ? p1 : p2);
            float ce = lse - (pt - m);            // -log_softmax[t]
            float aw = fabsf(pcv[j]);

            s_ce  += ce;
            s_cew += ce * aw;
            s_mw  += aw;
            bool aligned = (tdv[j] > 0.f && t == 2) || (tdv[j] < 0.f && t == 0);
            s_tr += aligned ? 1.0f : 0.0f;
        }

        if (it + 1 < ITERS) {
            A0 = nA0; A1 = nA1; A2 = nA2; T = nT; P = nP; D = nD;
            wi = nwi;
        }
    }

    // -------- wave butterfly + LDS block reduce --------
    #pragma unroll
    for (int off = 32; off >= 1; off >>= 1) {
        s_cew += __shfl_down(s_cew, off, 64);
        s_ce  += __shfl_down(s_ce , off, 64);
        s_mw  += __shfl_down(s_mw , off, 64);
        s_tr  += __shfl_down(s_tr , off, 64);
    }

    __shared__ float red[WPB][4];
    if (l == 0) {
        red[wave][0] = s_cew;
        red[wave][1] = s_ce;
        red[wave][2] = s_mw;
        red[wave][3] = s_tr;
    }
    __syncthreads();

    // -------- per-block atomics + last-block finalize --------
    if (threadIdx.x == 0) {
        float r0 = red[0][0] + red[1][0] + red[2][0] + red[3][0];
        float r1 = red[0][1] + red[1][1] + red[2][1] + red[3][1];
        float r2 = red[0][2] + red[1][2] + red[2][2] + red[3][2];
        float r3 = red[0][3] + red[1][3] + red[2][3] + red[3][3];

        atomicAdd(&sums[0], r0);
        atomicAdd(&sums[1], r1);
        atomicAdd(&sums[2], r2);
        atomicAdd(&sums[3], r3);

        __threadfence();                       // release: sums visible before count
        unsigned old = atomicAdd(count, 1u);
        if (old == BLOCKS - 1) {
            float cew = atomicAdd(&sums[0], 0.0f);
            float ce  = atomicAdd(&sums[1], 0.0f);
            float mw  = atomicAdd(&sums[2], 0.0f);
            float tr  = atomicAdd(&sums[3], 0.0f);

            const float invB = 1.0f / (float)B_TOTAL;
            float cew_mean = cew * invB;             // mean(ce * |pc|)
            float ce_mean  = ce  * invB;             // mean(ce)
            float mw_mean  = mw  * invB + 1e-8f;     // mean(|pc|) + EPS
            float tr_mean  = -0.1f * tr * invB;      // mean(trend_alignment)
            out[0] = 0.85f * (cew_mean / mw_mean) + 0.15f * ce_mean + 0.1f * tr_mean;
        }
    }
}

extern "C" void kernel_launch(void* const* d_in, const int* in_sizes, int n_in,
                              void* d_out, int out_size, void* d_ws, size_t ws_size,
                              hipStream_t stream) {
    const float* preds   = (const float*)d_in[0];
    const int*   targets = (const int*  )d_in[1];
    const float* pc      = (const float*)d_in[2];
    const float* td      = (const float*)d_in[3];
    float* out  = (float*)d_out;
    float* sums = (float*)d_ws;
    unsigned int* count = (unsigned int*)((char*)d_ws + 4 * sizeof(float));

    // d_ws is poisoned 0xAA before every timed launch — zero accumulators + counter.
    hipMemsetAsync(d_ws, 0, 5 * sizeof(float), stream);

    trading_loss_fused<<<BLOCKS, THREADS, 0, stream>>>(preds, targets, pc, td,
                                                       sums, count, out);
}